// Round 9
// baseline (280.574 us; speedup 1.0000x reference)
//
#include <hip/hip_runtime.h>
#include <hip/hip_bf16.h>

#define S_LEN 2048
#define NHEADS 8
#define DHEAD 64
#define NBATCH 4
#define DMODEL 512

typedef __attribute__((ext_vector_type(8))) short short8;
typedef __attribute__((ext_vector_type(4))) short short4v;
typedef __attribute__((ext_vector_type(4))) float f32x4;

__device__ __forceinline__ short f2bf(float f) {
    unsigned int u = __builtin_bit_cast(unsigned int, f);
    u = (u + 0x7fffu + ((u >> 16) & 1u)) >> 16;
    return (short)u;
}

// ---------------- Er f32 -> bf16 ----------------
__global__ __launch_bounds__(256) void er_convert(const float* __restrict__ er,
                                                  unsigned short* __restrict__ erb) {
    int i = (blockIdx.x * 256 + threadIdx.x) * 4;
    float4 v = *(const float4*)(er + i);
    short4v s;
    s[0] = f2bf(v.x); s[1] = f2bf(v.y); s[2] = f2bf(v.z); s[3] = f2bf(v.w);
    *(short4v*)(erb + i) = s;
}

// ---------------- QKV projection: y[m,n] = sum_k x[m,k]*W[n,k] + b[n] ----------------
// Q,K bf16 in [mat][b][h][s][dh]; V written TRANSPOSED: [b][h][dh][s]
__global__ __launch_bounds__(256) void qkv_gemm(
    const float* __restrict__ x,
    const float* __restrict__ Wq, const float* __restrict__ bq,
    const float* __restrict__ Wk, const float* __restrict__ bk,
    const float* __restrict__ Wv, const float* __restrict__ bv,
    unsigned short* __restrict__ qkv)
{
    __shared__ __align__(16) short smem[64 * 136];   // xt(128*40) + wt(64*40) carved; reused for V transpose
    short* xt = smem;
    short* wt = smem + 128 * 40;
    const int tid = threadIdx.x;
    const int w = tid >> 6;
    const int l = tid & 63;
    const int lrow = l & 15, lgrp = l >> 4;
    const int m0 = blockIdx.x * 128;
    const int nb = blockIdx.y;
    const int mat = nb >> 3, hh = nb & 7;
    const float* W    = (mat == 0) ? Wq : ((mat == 1) ? Wk : Wv);
    const float* bias = (mat == 0) ? bq : ((mat == 1) ? bk : bv);
    const int n0 = hh * 64;

    f32x4 acc[2][4];
    #pragma unroll
    for (int i = 0; i < 2; i++)
        #pragma unroll
        for (int j = 0; j < 4; j++) acc[i][j] = (f32x4)0.0f;

    const int xrow = tid >> 1, xseg = tid & 1;   // 128 rows, 16 f32 each
    const int wrow = tid >> 2, wseg = tid & 3;   // 64 rows, 8 f32 each

    for (int k0 = 0; k0 < DMODEL; k0 += 32) {
        const float* xs = x + (size_t)(m0 + xrow) * DMODEL + k0 + xseg * 16;
        float4 a0 = *(const float4*)(xs);
        float4 a1 = *(const float4*)(xs + 4);
        float4 a2 = *(const float4*)(xs + 8);
        float4 a3 = *(const float4*)(xs + 12);
        const float* wsrc = W + (size_t)(n0 + wrow) * DMODEL + k0 + wseg * 8;
        float4 b0 = *(const float4*)(wsrc);
        float4 b1 = *(const float4*)(wsrc + 4);
        short8 sa0, sa1, sb;
        sa0[0]=f2bf(a0.x); sa0[1]=f2bf(a0.y); sa0[2]=f2bf(a0.z); sa0[3]=f2bf(a0.w);
        sa0[4]=f2bf(a1.x); sa0[5]=f2bf(a1.y); sa0[6]=f2bf(a1.z); sa0[7]=f2bf(a1.w);
        sa1[0]=f2bf(a2.x); sa1[1]=f2bf(a2.y); sa1[2]=f2bf(a2.z); sa1[3]=f2bf(a2.w);
        sa1[4]=f2bf(a3.x); sa1[5]=f2bf(a3.y); sa1[6]=f2bf(a3.z); sa1[7]=f2bf(a3.w);
        sb[0]=f2bf(b0.x); sb[1]=f2bf(b0.y); sb[2]=f2bf(b0.z); sb[3]=f2bf(b0.w);
        sb[4]=f2bf(b1.x); sb[5]=f2bf(b1.y); sb[6]=f2bf(b1.z); sb[7]=f2bf(b1.w);
        *(short8*)(xt + xrow * 40 + xseg * 16)     = sa0;
        *(short8*)(xt + xrow * 40 + xseg * 16 + 8) = sa1;
        *(short8*)(wt + wrow * 40 + wseg * 8)      = sb;
        __syncthreads();
        #pragma unroll
        for (int nc = 0; nc < 4; nc++) {
            short8 bfrag = *(const short8*)(wt + (nc * 16 + lrow) * 40 + lgrp * 8);
            #pragma unroll
            for (int mf = 0; mf < 2; mf++) {
                short8 afrag = *(const short8*)(xt + (w * 32 + mf * 16 + lrow) * 40 + lgrp * 8);
                acc[mf][nc] = __builtin_amdgcn_mfma_f32_16x16x32_bf16(afrag, bfrag, acc[mf][nc], 0, 0, 0);
            }
        }
        __syncthreads();
    }

    const int b  = m0 >> 11;           // m0 / 2048
    const int s0 = m0 & (S_LEN - 1);
    if (mat == 2) {
        // transpose through LDS, store V^T [b][h][d][s] coalesced
        short* vl = smem;   // 64 x 136 shorts
        #pragma unroll
        for (int nc = 0; nc < 4; nc++) {
            const int d = nc * 16 + lrow;
            const float bias_v = bias[n0 + d];
            #pragma unroll
            for (int mf = 0; mf < 2; mf++)
                #pragma unroll
                for (int r = 0; r < 4; r++) {
                    const int sl = w * 32 + mf * 16 + lgrp * 4 + r;
                    vl[d * 136 + sl] = f2bf(acc[mf][nc][r] + bias_v);
                }
        }
        __syncthreads();
        unsigned short* ob = qkv + (((size_t)2 * NBATCH + b) * NHEADS + hh) * S_LEN * DHEAD;
        #pragma unroll
        for (int kch = 0; kch < 4; kch++) {
            const int c = kch * 256 + tid;
            const int d = c >> 4, seg = c & 15;
            short8 ch = *(const short8*)(vl + d * 136 + seg * 8);
            *(short8*)(ob + (size_t)d * S_LEN + s0 + seg * 8) = ch;
        }
    } else {
        unsigned short* ob = qkv + (((size_t)mat * NBATCH + b) * NHEADS + hh) * S_LEN * DHEAD;
        #pragma unroll
        for (int nc = 0; nc < 4; nc++) {
            const int d = nc * 16 + lrow;
            const float bias_v = bias[n0 + d];
            #pragma unroll
            for (int mf = 0; mf < 2; mf++) {
                #pragma unroll
                for (int r = 0; r < 4; r++) {
                    int srow = s0 + w * 32 + mf * 16 + lgrp * 4 + r;
                    ob[(size_t)srow * DHEAD + d] = (unsigned short)f2bf(acc[mf][nc][r] + bias_v);
                }
            }
        }
    }
}

// ---------------- fused causal attention with relative (skew) bias ----------------
// scores[s,t] = (q[s].k[t] + q[s].Er[t-s+S-1]) / 8, t <= s
// No-max softmax (|scores| bounded); denominator via MFMA vs ones-fragment.
// BARRIER-FREE wave-flash: each wave computes a 16-row strip over KVBLK=32
// tiles; K/Er prefetched one tile ahead into registers (L2-resident), V
// loaded just-in-time. Only LDS = private 1.25KB P-bounce per wave.
// t-split x4: waves of a block take tiles it = w, w+4, ... of the SAME strip
// and merge (o, lsum) at the end (exact: un-shifted exp partials just add).
// HW exp: inline v_exp_f32 (exp2f w/o fast-math = ~25-inst OCML polynomial).
__global__ __launch_bounds__(256) void rga_attn(
    const unsigned short* __restrict__ qkv,
    const unsigned short* __restrict__ er,
    float* __restrict__ out)
{
    __shared__ __align__(16) unsigned short plds[4][16 * 40];  // per-wave P, 80B-stride rows
    __shared__ __align__(16) float obuf[3][1024];              // merge: o from waves 1..3
    __shared__ __align__(16) float lbuf[3][16];                // merge: lsum

    const int tid = threadIdx.x;
    const int w = tid >> 6;
    const int l = tid & 63;
    const int lrow = l & 15, lgrp = l >> 4;
    const int bh = blockIdx.y;
    const int b = bh >> 3, hh = bh & 7;
    const int sid = 127 - (int)((blockIdx.x + 9 * blockIdx.y) & 127);  // balanced, heavy-first
    const int s0 = sid * 16;
    const int nt = (sid >> 1) + 1;

    const unsigned short* qp  = qkv + (size_t)bh * S_LEN * DHEAD;
    const unsigned short* kp  = qkv + ((size_t)(NBATCH * NHEADS) + bh) * S_LEN * DHEAD;
    const unsigned short* vtg = qkv + ((size_t)(2 * NBATCH * NHEADS) + bh) * S_LEN * DHEAD; // [d][s]

    short8 aq0, aq1;
    {
        const unsigned short* qr = qp + (size_t)(s0 + lrow) * DHEAD + lgrp * 8;
        aq0 = *(const short8*)(qr);
        aq1 = *(const short8*)(qr + 32);
    }

    short8 ones;
    #pragma unroll
    for (int e = 0; e < 8; e++) ones[e] = (short)0x3F80;   // bf16 1.0

    f32x4 o[4], lsum;
    lsum = (f32x4)0.0f;
    #pragma unroll
    for (int n = 0; n < 4; n++) o[n] = (f32x4)0.0f;

    // prologue: prefetch K + Er fragments for tile it = w (rows always in-bounds)
    short8 kf0[2], kf1[2], ef0[3], ef1[3];
    {
        const int t0p = w << 5;
        #pragma unroll
        for (int u = 0; u < 2; u++) {
            const unsigned short* kq = kp + (size_t)(t0p + u * 16 + lrow) * DHEAD + lgrp * 8;
            kf0[u] = *(const short8*)(kq);
            kf1[u] = *(const short8*)(kq + 32);
        }
        const int r_lo = t0p - s0 + (S_LEN - 16);
        #pragma unroll
        for (int f = 0; f < 3; f++) {
            int rr = r_lo + f * 16 + lrow;
            rr = rr < 0 ? 0 : (rr > (S_LEN - 1) ? (S_LEN - 1) : rr);
            const unsigned short* ep = er + (size_t)rr * DHEAD + lgrp * 8;
            ef0[f] = *(const short8*)(ep);
            ef1[f] = *(const short8*)(ep + 32);
        }
    }

    unsigned short* pw = plds[w];

    for (int it = w; it < nt; it += 4) {
        const int t0 = it << 5;
        // ---- QEr band (3 frags cover jr in [0,47]) + QK^T ----
        f32x4 qe[3], sfr[2];
        __builtin_amdgcn_s_setprio(1);
        #pragma unroll
        for (int f = 0; f < 3; f++) {
            f32x4 a = (f32x4)0.0f;
            a = __builtin_amdgcn_mfma_f32_16x16x32_bf16(aq0, ef0[f], a, 0, 0, 0);
            a = __builtin_amdgcn_mfma_f32_16x16x32_bf16(aq1, ef1[f], a, 0, 0, 0);
            qe[f] = a;
        }
        #pragma unroll
        for (int u = 0; u < 2; u++) {
            f32x4 a = (f32x4)0.0f;
            a = __builtin_amdgcn_mfma_f32_16x16x32_bf16(aq0, kf0[u], a, 0, 0, 0);
            a = __builtin_amdgcn_mfma_f32_16x16x32_bf16(aq1, kf1[u], a, 0, 0, 0);
            sfr[u] = a;
        }
        __builtin_amdgcn_s_setprio(0);

        // ---- prefetch tile it+4 (lands during softmax/PV of this + next tiles) ----
        if (it + 4 < nt) {
            const int t0n = t0 + 128;
            #pragma unroll
            for (int u = 0; u < 2; u++) {
                const unsigned short* kq = kp + (size_t)(t0n + u * 16 + lrow) * DHEAD + lgrp * 8;
                kf0[u] = *(const short8*)(kq);
                kf1[u] = *(const short8*)(kq + 32);
            }
            const int r_lo = t0n - s0 + (S_LEN - 16);
            #pragma unroll
            for (int f = 0; f < 3; f++) {
                int rr = r_lo + f * 16 + lrow;
                rr = rr < 0 ? 0 : (rr > (S_LEN - 1) ? (S_LEN - 1) : rr);
                const unsigned short* ep = er + (size_t)rr * DHEAD + lgrp * 8;
                ef0[f] = *(const short8*)(ep);
                ef1[f] = *(const short8*)(ep + 32);
            }
        }

        // ---- V fragments, just-in-time (consumed after softmax ~500cyc later) ----
        short8 vb[4];
        #pragma unroll
        for (int n = 0; n < 4; n++)
            vb[n] = *(const short8*)(vtg + (size_t)(n * 16 + lrow) * S_LEN + t0 + lgrp * 8);

        // ---- band gather + mask + exp (v_exp_f32) + P pack to LDS ----
        #pragma unroll
        for (int r = 0; r < 4; r++) {
            const int si = lgrp * 4 + r;
            const int sg = s0 + si;
            const int dd = lrow - si + 15;            // [0,30]
            const int srcl = (l & 48) | (dd & 15);
            const int hi = dd >> 4;
            float sh0 = __shfl(qe[0][r], srcl);
            float sh1 = __shfl(qe[1][r], srcl);
            float sh2 = __shfl(qe[2][r], srcl);
            const float relA = hi ? sh1 : sh0;
            const float relB = hi ? sh2 : sh1;
            float sA = (sfr[0][r] + relA) * 0.18033688f;   // /8 /ln2
            float sB = (sfr[1][r] + relB) * 0.18033688f;
            float pA, pB;
            asm("v_exp_f32 %0, %1\ns_nop 1" : "=v"(pA) : "v"(sA));
            asm("v_exp_f32 %0, %1\ns_nop 1" : "=v"(pB) : "v"(sB));
            pA = (t0 + lrow      <= sg) ? pA : 0.0f;
            pB = (t0 + 16 + lrow <= sg) ? pB : 0.0f;
            unsigned pk;
            asm("v_cvt_pk_bf16_f32 %0, %1, %2" : "=v"(pk) : "v"(pA), "v"(pB));
            const int rot = (si & 3) << 4;
            char* pr = (char*)pw + si * 80;
            *(unsigned short*)(pr + ((lrow * 2) ^ rot))      = (unsigned short)pk;
            *(unsigned short*)(pr + ((32 + lrow * 2) ^ rot)) = (unsigned short)(pk >> 16);
        }
        asm volatile("s_waitcnt lgkmcnt(0)" ::: "memory");
        __builtin_amdgcn_sched_barrier(0);
        // ---- PV + row-sum (denominator) ----
        __builtin_amdgcn_s_setprio(1);
        short8 pa = *(const short8*)((const char*)pw + lrow * 80 +
                                     ((lgrp * 16) ^ ((lrow & 3) << 4)));
        lsum = __builtin_amdgcn_mfma_f32_16x16x32_bf16(pa, ones, lsum, 0, 0, 0);
        #pragma unroll
        for (int n = 0; n < 4; n++)
            o[n] = __builtin_amdgcn_mfma_f32_16x16x32_bf16(pa, vb[n], o[n], 0, 0, 0);
        __builtin_amdgcn_s_setprio(0);
    }

    // ---- cross-wave merge of t-split partials: plain sums ----
    if (w > 0) {
        #pragma unroll
        for (int n = 0; n < 4; n++)
            *(f32x4*)&obuf[w - 1][(n * 16 + lrow) * 16 + lgrp * 4] = o[n];
        if (lrow == 0)
            *(f32x4*)&lbuf[w - 1][lgrp * 4] = lsum;
    }
    __syncthreads();
    if (w == 0) {
        #pragma unroll
        for (int m = 0; m < 3; m++) {
            lsum += *(const f32x4*)&lbuf[m][lgrp * 4];
            #pragma unroll
            for (int n = 0; n < 4; n++)
                o[n] += *(const f32x4*)&obuf[m][(n * 16 + lrow) * 16 + lgrp * 4];
        }
        #pragma unroll
        for (int r = 0; r < 4; r++) {
            const int sg = s0 + lgrp * 4 + r;
            const float inv = 1.0f / lsum[r];
            float* orow = out + ((size_t)b * S_LEN + sg) * DMODEL + hh * DHEAD;
            #pragma unroll
            for (int n = 0; n < 4; n++)
                orow[n * 16 + lrow] = o[n][r] * inv;
        }
    }
}

extern "C" void kernel_launch(void* const* d_in, const int* in_sizes, int n_in,
                              void* d_out, int out_size, void* d_ws, size_t ws_size,
                              hipStream_t stream) {
    const float* x  = (const float*)d_in[0];
    const float* Wq = (const float*)d_in[1];
    const float* bq = (const float*)d_in[2];
    const float* Wk = (const float*)d_in[3];
    const float* bk = (const float*)d_in[4];
    const float* Wv = (const float*)d_in[5];
    const float* bv = (const float*)d_in[6];
    const float* Er = (const float*)d_in[7];

    unsigned short* ws_qkv = (unsigned short*)d_ws;                       // Q,K [b][h][s][d]; V^T [b][h][d][s]
    unsigned short* ws_er  = ws_qkv + (size_t)3 * NBATCH * NHEADS * S_LEN * DHEAD;

    er_convert<<<dim3(128), dim3(256), 0, stream>>>(Er, ws_er);
    qkv_gemm<<<dim3(64, 24), dim3(256), 0, stream>>>(x, Wq, bq, Wk, bk, Wv, bv, ws_qkv);
    rga_attn<<<dim3(128, 32), dim3(256), 0, stream>>>(ws_qkv, ws_er, (float*)d_out);
}

// Round 10
// 175.126 us; speedup vs baseline: 1.6021x; 1.6021x over previous
//
#include <hip/hip_runtime.h>
#include <hip/hip_bf16.h>

#define S_LEN 2048
#define NHEADS 8
#define DHEAD 64
#define NBATCH 4
#define DMODEL 512

typedef __attribute__((ext_vector_type(8))) short short8;
typedef __attribute__((ext_vector_type(4))) short short4v;
typedef __attribute__((ext_vector_type(4))) float f32x4;

__device__ __forceinline__ short f2bf(float f) {
    unsigned int u = __builtin_bit_cast(unsigned int, f);
    u = (u + 0x7fffu + ((u >> 16) & 1u)) >> 16;
    return (short)u;
}

// ---------------- Er f32 -> bf16 ----------------
__global__ __launch_bounds__(256) void er_convert(const float* __restrict__ er,
                                                  unsigned short* __restrict__ erb) {
    int i = (blockIdx.x * 256 + threadIdx.x) * 4;
    float4 v = *(const float4*)(er + i);
    short4v s;
    s[0] = f2bf(v.x); s[1] = f2bf(v.y); s[2] = f2bf(v.z); s[3] = f2bf(v.w);
    *(short4v*)(erb + i) = s;
}

// ---------------- QKV projection: y[m,n] = sum_k x[m,k]*W[n,k] + b[n] ----------------
// Q,K bf16 in [mat][b][h][s][dh]; V written TRANSPOSED: [b][h][dh][s].
// Q is PRE-SCALED by 1/(8*ln2): Q carries the softmax scale through both
// the QK^T and QEr products, so the attention loop does exp2(sum) directly.
__global__ __launch_bounds__(256) void qkv_gemm(
    const float* __restrict__ x,
    const float* __restrict__ Wq, const float* __restrict__ bq,
    const float* __restrict__ Wk, const float* __restrict__ bk,
    const float* __restrict__ Wv, const float* __restrict__ bv,
    unsigned short* __restrict__ qkv)
{
    __shared__ __align__(16) short smem[64 * 136];   // xt(128*40) + wt(64*40) carved; reused for V transpose
    short* xt = smem;
    short* wt = smem + 128 * 40;
    const int tid = threadIdx.x;
    const int w = tid >> 6;
    const int l = tid & 63;
    const int lrow = l & 15, lgrp = l >> 4;
    const int m0 = blockIdx.x * 128;
    const int nb = blockIdx.y;
    const int mat = nb >> 3, hh = nb & 7;
    const float* W    = (mat == 0) ? Wq : ((mat == 1) ? Wk : Wv);
    const float* bias = (mat == 0) ? bq : ((mat == 1) ? bk : bv);
    const int n0 = hh * 64;

    f32x4 acc[2][4];
    #pragma unroll
    for (int i = 0; i < 2; i++)
        #pragma unroll
        for (int j = 0; j < 4; j++) acc[i][j] = (f32x4)0.0f;

    const int xrow = tid >> 1, xseg = tid & 1;   // 128 rows, 16 f32 each
    const int wrow = tid >> 2, wseg = tid & 3;   // 64 rows, 8 f32 each

    for (int k0 = 0; k0 < DMODEL; k0 += 32) {
        const float* xs = x + (size_t)(m0 + xrow) * DMODEL + k0 + xseg * 16;
        float4 a0 = *(const float4*)(xs);
        float4 a1 = *(const float4*)(xs + 4);
        float4 a2 = *(const float4*)(xs + 8);
        float4 a3 = *(const float4*)(xs + 12);
        const float* wsrc = W + (size_t)(n0 + wrow) * DMODEL + k0 + wseg * 8;
        float4 b0 = *(const float4*)(wsrc);
        float4 b1 = *(const float4*)(wsrc + 4);
        short8 sa0, sa1, sb;
        sa0[0]=f2bf(a0.x); sa0[1]=f2bf(a0.y); sa0[2]=f2bf(a0.z); sa0[3]=f2bf(a0.w);
        sa0[4]=f2bf(a1.x); sa0[5]=f2bf(a1.y); sa0[6]=f2bf(a1.z); sa0[7]=f2bf(a1.w);
        sa1[0]=f2bf(a2.x); sa1[1]=f2bf(a2.y); sa1[2]=f2bf(a2.z); sa1[3]=f2bf(a2.w);
        sa1[4]=f2bf(a3.x); sa1[5]=f2bf(a3.y); sa1[6]=f2bf(a3.z); sa1[7]=f2bf(a3.w);
        sb[0]=f2bf(b0.x); sb[1]=f2bf(b0.y); sb[2]=f2bf(b0.z); sb[3]=f2bf(b0.w);
        sb[4]=f2bf(b1.x); sb[5]=f2bf(b1.y); sb[6]=f2bf(b1.z); sb[7]=f2bf(b1.w);
        *(short8*)(xt + xrow * 40 + xseg * 16)     = sa0;
        *(short8*)(xt + xrow * 40 + xseg * 16 + 8) = sa1;
        *(short8*)(wt + wrow * 40 + wseg * 8)      = sb;
        __syncthreads();
        #pragma unroll
        for (int nc = 0; nc < 4; nc++) {
            short8 bfrag = *(const short8*)(wt + (nc * 16 + lrow) * 40 + lgrp * 8);
            #pragma unroll
            for (int mf = 0; mf < 2; mf++) {
                short8 afrag = *(const short8*)(xt + (w * 32 + mf * 16 + lrow) * 40 + lgrp * 8);
                acc[mf][nc] = __builtin_amdgcn_mfma_f32_16x16x32_bf16(afrag, bfrag, acc[mf][nc], 0, 0, 0);
            }
        }
        __syncthreads();
    }

    const int b  = m0 >> 11;           // m0 / 2048
    const int s0 = m0 & (S_LEN - 1);
    if (mat == 2) {
        // transpose through LDS, store V^T [b][h][d][s] coalesced
        short* vl = smem;   // 64 x 136 shorts
        #pragma unroll
        for (int nc = 0; nc < 4; nc++) {
            const int d = nc * 16 + lrow;
            const float bias_v = bias[n0 + d];
            #pragma unroll
            for (int mf = 0; mf < 2; mf++)
                #pragma unroll
                for (int r = 0; r < 4; r++) {
                    const int sl = w * 32 + mf * 16 + lgrp * 4 + r;
                    vl[d * 136 + sl] = f2bf(acc[mf][nc][r] + bias_v);
                }
        }
        __syncthreads();
        unsigned short* ob = qkv + (((size_t)2 * NBATCH + b) * NHEADS + hh) * S_LEN * DHEAD;
        #pragma unroll
        for (int kch = 0; kch < 4; kch++) {
            const int c = kch * 256 + tid;
            const int d = c >> 4, seg = c & 15;
            short8 ch = *(const short8*)(vl + d * 136 + seg * 8);
            *(short8*)(ob + (size_t)d * S_LEN + s0 + seg * 8) = ch;
        }
    } else {
        const float oscale = (mat == 0) ? 0.18033688f : 1.0f;   // Q: 1/(8*ln2)
        unsigned short* ob = qkv + (((size_t)mat * NBATCH + b) * NHEADS + hh) * S_LEN * DHEAD;
        #pragma unroll
        for (int nc = 0; nc < 4; nc++) {
            const int d = nc * 16 + lrow;
            const float bias_v = bias[n0 + d];
            #pragma unroll
            for (int mf = 0; mf < 2; mf++) {
                #pragma unroll
                for (int r = 0; r < 4; r++) {
                    int srow = s0 + w * 32 + mf * 16 + lgrp * 4 + r;
                    ob[(size_t)srow * DHEAD + d] =
                        (unsigned short)f2bf((acc[mf][nc][r] + bias_v) * oscale);
                }
            }
        }
    }
}

// ---------------- fused causal attention with relative (skew) bias ----------------
// scores pre-scaled into Q: P = exp2(q'.k[t] + q'.Er[t-s+S-1]), t <= s.
// No-max softmax (|scores| bounded); denominator via MFMA vs ones-fragment.
// 2 waves x 16 q-rows = 32-row strip, KVBLK=64. 2048 blocks, 21.2KB LDS.
// sid = 63-((x+2y)&63): per-CU strips spaced 8 apart, heavy-first.
// Er band prefetched into regs one tile ahead. HW v_exp_f32 + cvt_pk P-pack
// (R9-proven VALU cuts grafted onto the R8 structure).
__global__ __launch_bounds__(128) void rga_attn(
    const unsigned short* __restrict__ qkv,
    const unsigned short* __restrict__ er,
    float* __restrict__ out)
{
    __shared__ __align__(16) unsigned short klds[64 * 64];      // [t][d], rows 128B xor-swizzled
    __shared__ __align__(16) unsigned short vt[64 * 72];        // [d][t], stride 72 (pad)
    __shared__ __align__(16) unsigned short plds[2][16 * 64];   // per-wave P, rows 128B xor-swizzled

    const int tid = threadIdx.x;
    const int w = tid >> 6;
    const int l = tid & 63;
    const int lrow = l & 15, lgrp = l >> 4;
    const int bh = blockIdx.y;
    const int b = bh >> 3, hh = bh & 7;
    const int sid = 63 - (int)((blockIdx.x + 2 * blockIdx.y) & 63);
    const int q0 = sid * 32;
    const int s_base = q0 + w * 16;
    const int nt = (sid >> 1) + 1;

    const unsigned short* qp  = qkv + (size_t)bh * S_LEN * DHEAD;
    const unsigned short* kp  = qkv + ((size_t)(NBATCH * NHEADS) + bh) * S_LEN * DHEAD;
    const unsigned short* vtg = qkv + ((size_t)(2 * NBATCH * NHEADS) + bh) * S_LEN * DHEAD; // [d][s]

    short8 aq[2];
    {
        const unsigned short* qr = qp + (size_t)(s_base + lrow) * DHEAD + lgrp * 8;
        aq[0] = *(const short8*)(qr);
        aq[1] = *(const short8*)(qr + 32);
    }

    short8 ones;
    #pragma unroll
    for (int e = 0; e < 8; e++) ones[e] = (short)0x3F80;   // bf16 1.0

    f32x4 o[4], lsum;
    lsum = (f32x4)0.0f;
    #pragma unroll
    for (int n = 0; n < 4; n++) o[n] = (f32x4)0.0f;

    // staging: 512 b128 units each for K and V; 128 threads x 4 units
    const int trb = tid >> 3, seg = tid & 7;   // unit j: row trb + 16j
    short8 kreg[4], vreg[4];
    #pragma unroll
    for (int j = 0; j < 4; j++) {
        kreg[j] = *(const short8*)(kp + (size_t)(trb + 16 * j) * DHEAD + seg * 8);
        vreg[j] = *(const short8*)(vtg + (size_t)(trb + 16 * j) * S_LEN + seg * 8);
    }
    // Er band prefetch for tile 0
    short8 ereg0[5], ereg1[5];
    {
        const int r_lo = -s_base + (S_LEN - 16);
        #pragma unroll
        for (int f = 0; f < 5; f++) {
            int rr = r_lo + f * 16 + lrow;
            rr = rr < 0 ? 0 : (rr > (S_LEN - 1) ? (S_LEN - 1) : rr);
            const unsigned short* ep = er + (size_t)rr * DHEAD + lgrp * 8;
            ereg0[f] = *(const short8*)(ep);
            ereg1[f] = *(const short8*)(ep + 32);
        }
    }

    unsigned short* pw = plds[w];

    for (int it = 0; it < nt; it++) {
        const int t0 = it << 6;
        __syncthreads();   // previous tile's compute done; LDS free
        #pragma unroll
        for (int j = 0; j < 4; j++) {
            const int tr = trb + 16 * j;
            *(short8*)((char*)klds + tr * 128 + ((seg * 16) ^ ((tr & 7) << 4))) = kreg[j];
            *(short8*)(vt + tr * 72 + seg * 8) = vreg[j];
        }
        __syncthreads();   // LDS tile ready

        // ---- QEr band (prefetched regs): 5 frags cover jr in [0,79] ----
        f32x4 qe[5];
        __builtin_amdgcn_s_setprio(1);
        #pragma unroll
        for (int f = 0; f < 5; f++) {
            f32x4 a = (f32x4)0.0f;
            a = __builtin_amdgcn_mfma_f32_16x16x32_bf16(aq[0], ereg0[f], a, 0, 0, 0);
            a = __builtin_amdgcn_mfma_f32_16x16x32_bf16(aq[1], ereg1[f], a, 0, 0, 0);
            qe[f] = a;
        }
        __builtin_amdgcn_s_setprio(0);

        if (it + 1 < nt) {   // issue next tile's K/V and Er loads; land during compute
            #pragma unroll
            for (int j = 0; j < 4; j++) {
                const int tr = trb + 16 * j;
                kreg[j] = *(const short8*)(kp + (size_t)(t0 + 64 + tr) * DHEAD + seg * 8);
                vreg[j] = *(const short8*)(vtg + (size_t)tr * S_LEN + t0 + 64 + seg * 8);
            }
            const int r_lo = t0 + 64 - s_base + (S_LEN - 16);
            #pragma unroll
            for (int f = 0; f < 5; f++) {
                int rr = r_lo + f * 16 + lrow;
                rr = rr < 0 ? 0 : (rr > (S_LEN - 1) ? (S_LEN - 1) : rr);
                const unsigned short* ep = er + (size_t)rr * DHEAD + lgrp * 8;
                ereg0[f] = *(const short8*)(ep);
                ereg1[f] = *(const short8*)(ep + 32);
            }
        }

        // ---- QK^T: 16 rows x 64 t ----
        f32x4 sfr[4];
        __builtin_amdgcn_s_setprio(1);
        #pragma unroll
        for (int u = 0; u < 4; u++) {
            const int trow = u * 16 + lrow;
            const char* kb = (const char*)klds + trow * 128;
            const int swz = (trow & 7) << 4;
            short8 kb0 = *(const short8*)(kb + ((lgrp * 16) ^ swz));
            short8 kb1 = *(const short8*)(kb + ((64 + lgrp * 16) ^ swz));
            f32x4 a = (f32x4)0.0f;
            a = __builtin_amdgcn_mfma_f32_16x16x32_bf16(aq[0], kb0, a, 0, 0, 0);
            a = __builtin_amdgcn_mfma_f32_16x16x32_bf16(aq[1], kb1, a, 0, 0, 0);
            sfr[u] = a;
        }
        __builtin_amdgcn_s_setprio(0);

        // ---- band gather + mask + exp2 (v_exp_f32) + cvt_pk pack -> LDS ----
        #pragma unroll
        for (int r = 0; r < 4; r++) {
            const int si = lgrp * 4 + r;
            const int sg = s_base + si;
            const int dd = lrow - si + 15;            // [0,30]
            const int srcl = (l & 48) | (dd & 15);
            const int hi = dd >> 4;
            float sh[5];
            #pragma unroll
            for (int f = 0; f < 5; f++) sh[f] = __shfl(qe[f][r], srcl);
            const int pswz = (si & 7) << 4;
            char* pr = (char*)pw + si * 128;
            float pe[4];
            #pragma unroll
            for (int u = 0; u < 4; u++) {
                const float rel = hi ? sh[u + 1] : sh[u];
                float sc = sfr[u][r] + rel;            // scale folded into Q
                float ex;
                asm("v_exp_f32 %0, %1\ns_nop 1" : "=v"(ex) : "v"(sc));
                pe[u] = ((t0 + u * 16 + lrow) <= sg) ? ex : 0.0f;
            }
            #pragma unroll
            for (int h2 = 0; h2 < 2; h2++) {
                unsigned pk;
                asm("v_cvt_pk_bf16_f32 %0, %1, %2"
                    : "=v"(pk) : "v"(pe[h2 * 2]), "v"(pe[h2 * 2 + 1]));
                *(unsigned short*)(pr + (((h2 * 32 + lrow) * 2) ^ pswz)) = (unsigned short)pk;
                *(unsigned short*)(pr + (((h2 * 32 + 16 + lrow) * 2) ^ pswz)) = (unsigned short)(pk >> 16);
            }
        }
        asm volatile("s_waitcnt lgkmcnt(0)" ::: "memory");
        __builtin_amdgcn_sched_barrier(0);
        // ---- PV + row-sum (denominator) ----
        __builtin_amdgcn_s_setprio(1);
        const int pswz2 = (lrow & 7) << 4;
        #pragma unroll
        for (int kk = 0; kk < 2; kk++) {
            short8 pa = *(const short8*)((const char*)pw + lrow * 128 +
                                         ((kk * 64 + lgrp * 16) ^ pswz2));
            lsum = __builtin_amdgcn_mfma_f32_16x16x32_bf16(pa, ones, lsum, 0, 0, 0);
            #pragma unroll
            for (int n = 0; n < 4; n++) {
                short8 vb = *(const short8*)(vt + (n * 16 + lrow) * 72 + kk * 32 + lgrp * 8);
                o[n] = __builtin_amdgcn_mfma_f32_16x16x32_bf16(pa, vb, o[n], 0, 0, 0);
            }
        }
        __builtin_amdgcn_s_setprio(0);
    }

    #pragma unroll
    for (int r = 0; r < 4; r++) {
        const int sg = s_base + lgrp * 4 + r;
        const float inv = 1.0f / lsum[r];
        float* orow = out + ((size_t)b * S_LEN + sg) * DMODEL + hh * DHEAD;
        #pragma unroll
        for (int n = 0; n < 4; n++)
            orow[n * 16 + lrow] = o[n][r] * inv;
    }
}

extern "C" void kernel_launch(void* const* d_in, const int* in_sizes, int n_in,
                              void* d_out, int out_size, void* d_ws, size_t ws_size,
                              hipStream_t stream) {
    const float* x  = (const float*)d_in[0];
    const float* Wq = (const float*)d_in[1];
    const float* bq = (const float*)d_in[2];
    const float* Wk = (const float*)d_in[3];
    const float* bk = (const float*)d_in[4];
    const float* Wv = (const float*)d_in[5];
    const float* bv = (const float*)d_in[6];
    const float* Er = (const float*)d_in[7];

    unsigned short* ws_qkv = (unsigned short*)d_ws;                       // Q,K [b][h][s][d]; V^T [b][h][d][s]
    unsigned short* ws_er  = ws_qkv + (size_t)3 * NBATCH * NHEADS * S_LEN * DHEAD;

    er_convert<<<dim3(128), dim3(256), 0, stream>>>(Er, ws_er);
    qkv_gemm<<<dim3(64, 24), dim3(256), 0, stream>>>(x, Wq, bq, Wk, bk, Wv, bv, ws_qkv);
    rga_attn<<<dim3(64, 32), dim3(128), 0, stream>>>(ws_qkv, ws_er, (float*)d_out);
}

// Round 11
// 169.449 us; speedup vs baseline: 1.6558x; 1.0335x over previous
//
#include <hip/hip_runtime.h>
#include <hip/hip_bf16.h>

#define S_LEN 2048
#define NHEADS 8
#define DHEAD 64
#define NBATCH 4
#define DMODEL 512
#define NJOBS 2048

typedef __attribute__((ext_vector_type(8))) short short8;
typedef __attribute__((ext_vector_type(4))) short short4v;
typedef __attribute__((ext_vector_type(4))) float f32x4;

__device__ __forceinline__ short f2bf(float f) {
    unsigned int u = __builtin_bit_cast(unsigned int, f);
    u = (u + 0x7fffu + ((u >> 16) & 1u)) >> 16;
    return (short)u;
}

// ---------------- Er f32 -> bf16 ----------------
__global__ __launch_bounds__(256) void er_convert(const float* __restrict__ er,
                                                  unsigned short* __restrict__ erb) {
    int i = (blockIdx.x * 256 + threadIdx.x) * 4;
    float4 v = *(const float4*)(er + i);
    short4v s;
    s[0] = f2bf(v.x); s[1] = f2bf(v.y); s[2] = f2bf(v.z); s[3] = f2bf(v.w);
    *(short4v*)(erb + i) = s;
}

// ---------------- QKV projection: y[m,n] = sum_k x[m,k]*W[n,k] + b[n] ----------------
// Q,K bf16 in [mat][b][h][s][dh]; V written TRANSPOSED: [b][h][dh][s].
// Q is PRE-SCALED by 1/(8*ln2): Q carries the softmax scale through both
// the QK^T and QEr products, so the attention loop does exp2(sum) directly.
__global__ __launch_bounds__(256) void qkv_gemm(
    const float* __restrict__ x,
    const float* __restrict__ Wq, const float* __restrict__ bq,
    const float* __restrict__ Wk, const float* __restrict__ bk,
    const float* __restrict__ Wv, const float* __restrict__ bv,
    unsigned short* __restrict__ qkv)
{
    __shared__ __align__(16) short smem[64 * 136];   // xt(128*40) + wt(64*40) carved; reused for V transpose
    short* xt = smem;
    short* wt = smem + 128 * 40;
    const int tid = threadIdx.x;
    const int w = tid >> 6;
    const int l = tid & 63;
    const int lrow = l & 15, lgrp = l >> 4;
    const int m0 = blockIdx.x * 128;
    const int nb = blockIdx.y;
    const int mat = nb >> 3, hh = nb & 7;
    const float* W    = (mat == 0) ? Wq : ((mat == 1) ? Wk : Wv);
    const float* bias = (mat == 0) ? bq : ((mat == 1) ? bk : bv);
    const int n0 = hh * 64;

    f32x4 acc[2][4];
    #pragma unroll
    for (int i = 0; i < 2; i++)
        #pragma unroll
        for (int j = 0; j < 4; j++) acc[i][j] = (f32x4)0.0f;

    const int xrow = tid >> 1, xseg = tid & 1;   // 128 rows, 16 f32 each
    const int wrow = tid >> 2, wseg = tid & 3;   // 64 rows, 8 f32 each

    for (int k0 = 0; k0 < DMODEL; k0 += 32) {
        const float* xs = x + (size_t)(m0 + xrow) * DMODEL + k0 + xseg * 16;
        float4 a0 = *(const float4*)(xs);
        float4 a1 = *(const float4*)(xs + 4);
        float4 a2 = *(const float4*)(xs + 8);
        float4 a3 = *(const float4*)(xs + 12);
        const float* wsrc = W + (size_t)(n0 + wrow) * DMODEL + k0 + wseg * 8;
        float4 b0 = *(const float4*)(wsrc);
        float4 b1 = *(const float4*)(wsrc + 4);
        short8 sa0, sa1, sb;
        sa0[0]=f2bf(a0.x); sa0[1]=f2bf(a0.y); sa0[2]=f2bf(a0.z); sa0[3]=f2bf(a0.w);
        sa0[4]=f2bf(a1.x); sa0[5]=f2bf(a1.y); sa0[6]=f2bf(a1.z); sa0[7]=f2bf(a1.w);
        sa1[0]=f2bf(a2.x); sa1[1]=f2bf(a2.y); sa1[2]=f2bf(a2.z); sa1[3]=f2bf(a2.w);
        sa1[4]=f2bf(a3.x); sa1[5]=f2bf(a3.y); sa1[6]=f2bf(a3.z); sa1[7]=f2bf(a3.w);
        sb[0]=f2bf(b0.x); sb[1]=f2bf(b0.y); sb[2]=f2bf(b0.z); sb[3]=f2bf(b0.w);
        sb[4]=f2bf(b1.x); sb[5]=f2bf(b1.y); sb[6]=f2bf(b1.z); sb[7]=f2bf(b1.w);
        *(short8*)(xt + xrow * 40 + xseg * 16)     = sa0;
        *(short8*)(xt + xrow * 40 + xseg * 16 + 8) = sa1;
        *(short8*)(wt + wrow * 40 + wseg * 8)      = sb;
        __syncthreads();
        #pragma unroll
        for (int nc = 0; nc < 4; nc++) {
            short8 bfrag = *(const short8*)(wt + (nc * 16 + lrow) * 40 + lgrp * 8);
            #pragma unroll
            for (int mf = 0; mf < 2; mf++) {
                short8 afrag = *(const short8*)(xt + (w * 32 + mf * 16 + lrow) * 40 + lgrp * 8);
                acc[mf][nc] = __builtin_amdgcn_mfma_f32_16x16x32_bf16(afrag, bfrag, acc[mf][nc], 0, 0, 0);
            }
        }
        __syncthreads();
    }

    const int b  = m0 >> 11;           // m0 / 2048
    const int s0 = m0 & (S_LEN - 1);
    if (mat == 2) {
        // transpose through LDS, store V^T [b][h][d][s] coalesced
        short* vl = smem;   // 64 x 136 shorts
        #pragma unroll
        for (int nc = 0; nc < 4; nc++) {
            const int d = nc * 16 + lrow;
            const float bias_v = bias[n0 + d];
            #pragma unroll
            for (int mf = 0; mf < 2; mf++)
                #pragma unroll
                for (int r = 0; r < 4; r++) {
                    const int sl = w * 32 + mf * 16 + lgrp * 4 + r;
                    vl[d * 136 + sl] = f2bf(acc[mf][nc][r] + bias_v);
                }
        }
        __syncthreads();
        unsigned short* ob = qkv + (((size_t)2 * NBATCH + b) * NHEADS + hh) * S_LEN * DHEAD;
        #pragma unroll
        for (int kch = 0; kch < 4; kch++) {
            const int c = kch * 256 + tid;
            const int d = c >> 4, seg = c & 15;
            short8 ch = *(const short8*)(vl + d * 136 + seg * 8);
            *(short8*)(ob + (size_t)d * S_LEN + s0 + seg * 8) = ch;
        }
    } else {
        const float oscale = (mat == 0) ? 0.18033688f : 1.0f;   // Q: 1/(8*ln2)
        unsigned short* ob = qkv + (((size_t)mat * NBATCH + b) * NHEADS + hh) * S_LEN * DHEAD;
        #pragma unroll
        for (int nc = 0; nc < 4; nc++) {
            const int d = nc * 16 + lrow;
            const float bias_v = bias[n0 + d];
            #pragma unroll
            for (int mf = 0; mf < 2; mf++) {
                #pragma unroll
                for (int r = 0; r < 4; r++) {
                    int srow = s0 + w * 32 + mf * 16 + lgrp * 4 + r;
                    ob[(size_t)srow * DHEAD + d] =
                        (unsigned short)f2bf((acc[mf][nc][r] + bias_v) * oscale);
                }
            }
        }
    }
}

// ---------------- fused causal attention with relative (skew) bias ----------------
// scores pre-scaled into Q: P = exp2(q'.k[t] + q'.Er[t-s+S-1]), t <= s.
// No-max softmax (|scores| bounded); denominator via MFMA vs ones-fragment.
// PERSISTENT WORK-STEALING: 1792 blocks (7/CU LDS cap) pull 32-row strip jobs
// heavy-first from a global atomic counter. Fixes R10's drain/imbalance
// (static 8 blocks/CU collapsed to 2.2 effective). Body = R10 verbatim.
__global__ __launch_bounds__(128) void rga_attn(
    const unsigned short* __restrict__ qkv,
    const unsigned short* __restrict__ er,
    float* __restrict__ out,
    int* __restrict__ counter)
{
    __shared__ __align__(16) unsigned short klds[64 * 64];      // [t][d], rows 128B xor-swizzled
    __shared__ __align__(16) unsigned short vt[64 * 72];        // [d][t], stride 72 (pad)
    __shared__ __align__(16) unsigned short plds[2][16 * 64];   // per-wave P, rows 128B xor-swizzled
    __shared__ int jobsh;

    const int tid = threadIdx.x;
    const int w = tid >> 6;
    const int l = tid & 63;
    const int lrow = l & 15, lgrp = l >> 4;
    const int trb = tid >> 3, seg = tid & 7;   // staging: unit j = row trb + 16j

    short8 ones;
    #pragma unroll
    for (int e = 0; e < 8; e++) ones[e] = (short)0x3F80;   // bf16 1.0

    for (;;) {
        if (tid == 0) jobsh = atomicAdd(counter, 1);
        __syncthreads();
        const int job = jobsh;
        __syncthreads();          // jobsh consumed before next job overwrites
        if (job >= NJOBS) return;

        const int sid = 63 - (job >> 5);       // heavy strips first
        const int bh  = job & 31;
        const int b = bh >> 3, hh = bh & 7;
        const int q0 = sid * 32;
        const int s_base = q0 + w * 16;
        const int nt = (sid >> 1) + 1;

        const unsigned short* qp  = qkv + (size_t)bh * S_LEN * DHEAD;
        const unsigned short* kp  = qkv + ((size_t)(NBATCH * NHEADS) + bh) * S_LEN * DHEAD;
        const unsigned short* vtg = qkv + ((size_t)(2 * NBATCH * NHEADS) + bh) * S_LEN * DHEAD;

        short8 aq[2];
        {
            const unsigned short* qr = qp + (size_t)(s_base + lrow) * DHEAD + lgrp * 8;
            aq[0] = *(const short8*)(qr);
            aq[1] = *(const short8*)(qr + 32);
        }

        f32x4 o[4], lsum;
        lsum = (f32x4)0.0f;
        #pragma unroll
        for (int n = 0; n < 4; n++) o[n] = (f32x4)0.0f;

        // prologue: prefetch tile 0 (K/V staged cooperatively, Er per wave)
        short8 kreg[4], vreg[4];
        #pragma unroll
        for (int j = 0; j < 4; j++) {
            kreg[j] = *(const short8*)(kp + (size_t)(trb + 16 * j) * DHEAD + seg * 8);
            vreg[j] = *(const short8*)(vtg + (size_t)(trb + 16 * j) * S_LEN + seg * 8);
        }
        short8 ereg0[5], ereg1[5];
        {
            const int r_lo = -s_base + (S_LEN - 16);
            #pragma unroll
            for (int f = 0; f < 5; f++) {
                int rr = r_lo + f * 16 + lrow;
                rr = rr < 0 ? 0 : (rr > (S_LEN - 1) ? (S_LEN - 1) : rr);
                const unsigned short* ep = er + (size_t)rr * DHEAD + lgrp * 8;
                ereg0[f] = *(const short8*)(ep);
                ereg1[f] = *(const short8*)(ep + 32);
            }
        }

        unsigned short* pw = plds[w];

        for (int it = 0; it < nt; it++) {
            const int t0 = it << 6;
            __syncthreads();   // previous tile's compute done; LDS free
            #pragma unroll
            for (int j = 0; j < 4; j++) {
                const int tr = trb + 16 * j;
                *(short8*)((char*)klds + tr * 128 + ((seg * 16) ^ ((tr & 7) << 4))) = kreg[j];
                *(short8*)(vt + tr * 72 + seg * 8) = vreg[j];
            }
            __syncthreads();   // LDS tile ready

            // ---- QEr band (prefetched regs): 5 frags cover jr in [0,79] ----
            f32x4 qe[5];
            __builtin_amdgcn_s_setprio(1);
            #pragma unroll
            for (int f = 0; f < 5; f++) {
                f32x4 a = (f32x4)0.0f;
                a = __builtin_amdgcn_mfma_f32_16x16x32_bf16(aq[0], ereg0[f], a, 0, 0, 0);
                a = __builtin_amdgcn_mfma_f32_16x16x32_bf16(aq[1], ereg1[f], a, 0, 0, 0);
                qe[f] = a;
            }
            __builtin_amdgcn_s_setprio(0);

            if (it + 1 < nt) {   // issue next tile's K/V and Er loads
                #pragma unroll
                for (int j = 0; j < 4; j++) {
                    const int tr = trb + 16 * j;
                    kreg[j] = *(const short8*)(kp + (size_t)(t0 + 64 + tr) * DHEAD + seg * 8);
                    vreg[j] = *(const short8*)(vtg + (size_t)tr * S_LEN + t0 + 64 + seg * 8);
                }
                const int r_lo = t0 + 64 - s_base + (S_LEN - 16);
                #pragma unroll
                for (int f = 0; f < 5; f++) {
                    int rr = r_lo + f * 16 + lrow;
                    rr = rr < 0 ? 0 : (rr > (S_LEN - 1) ? (S_LEN - 1) : rr);
                    const unsigned short* ep = er + (size_t)rr * DHEAD + lgrp * 8;
                    ereg0[f] = *(const short8*)(ep);
                    ereg1[f] = *(const short8*)(ep + 32);
                }
            }

            // ---- QK^T: 16 rows x 64 t ----
            f32x4 sfr[4];
            __builtin_amdgcn_s_setprio(1);
            #pragma unroll
            for (int u = 0; u < 4; u++) {
                const int trow = u * 16 + lrow;
                const char* kb = (const char*)klds + trow * 128;
                const int swz = (trow & 7) << 4;
                short8 kb0 = *(const short8*)(kb + ((lgrp * 16) ^ swz));
                short8 kb1 = *(const short8*)(kb + ((64 + lgrp * 16) ^ swz));
                f32x4 a = (f32x4)0.0f;
                a = __builtin_amdgcn_mfma_f32_16x16x32_bf16(aq[0], kb0, a, 0, 0, 0);
                a = __builtin_amdgcn_mfma_f32_16x16x32_bf16(aq[1], kb1, a, 0, 0, 0);
                sfr[u] = a;
            }
            __builtin_amdgcn_s_setprio(0);

            // ---- band gather + mask + exp2 (v_exp_f32) + cvt_pk pack -> LDS ----
            #pragma unroll
            for (int r = 0; r < 4; r++) {
                const int si = lgrp * 4 + r;
                const int sg = s_base + si;
                const int dd = lrow - si + 15;            // [0,30]
                const int srcl = (l & 48) | (dd & 15);
                const int hi = dd >> 4;
                float sh[5];
                #pragma unroll
                for (int f = 0; f < 5; f++) sh[f] = __shfl(qe[f][r], srcl);
                const int pswz = (si & 7) << 4;
                char* pr = (char*)pw + si * 128;
                float pe[4];
                #pragma unroll
                for (int u = 0; u < 4; u++) {
                    const float rel = hi ? sh[u + 1] : sh[u];
                    float sc = sfr[u][r] + rel;            // scale folded into Q
                    float ex;
                    asm("v_exp_f32 %0, %1\ns_nop 1" : "=v"(ex) : "v"(sc));
                    pe[u] = ((t0 + u * 16 + lrow) <= sg) ? ex : 0.0f;
                }
                #pragma unroll
                for (int h2 = 0; h2 < 2; h2++) {
                    unsigned pk;
                    asm("v_cvt_pk_bf16_f32 %0, %1, %2"
                        : "=v"(pk) : "v"(pe[h2 * 2]), "v"(pe[h2 * 2 + 1]));
                    *(unsigned short*)(pr + (((h2 * 32 + lrow) * 2) ^ pswz)) = (unsigned short)pk;
                    *(unsigned short*)(pr + (((h2 * 32 + 16 + lrow) * 2) ^ pswz)) = (unsigned short)(pk >> 16);
                }
            }
            asm volatile("s_waitcnt lgkmcnt(0)" ::: "memory");
            __builtin_amdgcn_sched_barrier(0);
            // ---- PV + row-sum (denominator) ----
            __builtin_amdgcn_s_setprio(1);
            const int pswz2 = (lrow & 7) << 4;
            #pragma unroll
            for (int kk = 0; kk < 2; kk++) {
                short8 pa = *(const short8*)((const char*)pw + lrow * 128 +
                                             ((kk * 64 + lgrp * 16) ^ pswz2));
                lsum = __builtin_amdgcn_mfma_f32_16x16x32_bf16(pa, ones, lsum, 0, 0, 0);
                #pragma unroll
                for (int n = 0; n < 4; n++) {
                    short8 vb = *(const short8*)(vt + (n * 16 + lrow) * 72 + kk * 32 + lgrp * 8);
                    o[n] = __builtin_amdgcn_mfma_f32_16x16x32_bf16(pa, vb, o[n], 0, 0, 0);
                }
            }
            __builtin_amdgcn_s_setprio(0);
        }

        #pragma unroll
        for (int r = 0; r < 4; r++) {
            const int sg = s_base + lgrp * 4 + r;
            const float inv = 1.0f / lsum[r];
            float* orow = out + ((size_t)b * S_LEN + sg) * DMODEL + hh * DHEAD;
            #pragma unroll
            for (int n = 0; n < 4; n++)
                orow[n * 16 + lrow] = o[n][r] * inv;
        }
        __syncthreads();   // all waves done with LDS before next job's staging
    }
}

extern "C" void kernel_launch(void* const* d_in, const int* in_sizes, int n_in,
                              void* d_out, int out_size, void* d_ws, size_t ws_size,
                              hipStream_t stream) {
    const float* x  = (const float*)d_in[0];
    const float* Wq = (const float*)d_in[1];
    const float* bq = (const float*)d_in[2];
    const float* Wk = (const float*)d_in[3];
    const float* bk = (const float*)d_in[4];
    const float* Wv = (const float*)d_in[5];
    const float* bv = (const float*)d_in[6];
    const float* Er = (const float*)d_in[7];

    unsigned short* ws_qkv = (unsigned short*)d_ws;                       // Q,K [b][h][s][d]; V^T [b][h][d][s]
    unsigned short* ws_er  = ws_qkv + (size_t)3 * NBATCH * NHEADS * S_LEN * DHEAD;
    int* ws_counter = (int*)(ws_er + (size_t)S_LEN * DHEAD);

    hipMemsetAsync(ws_counter, 0, sizeof(int), stream);
    er_convert<<<dim3(128), dim3(256), 0, stream>>>(Er, ws_er);
    qkv_gemm<<<dim3(64, 24), dim3(256), 0, stream>>>(x, Wq, bq, Wk, bk, Wv, bv, ws_qkv);
    rga_attn<<<dim3(1792), dim3(128), 0, stream>>>(ws_qkv, ws_er, (float*)d_out, ws_counter);
}